// Round 1
// baseline (1253.174 us; speedup 1.0000x reference)
//
#include <hip/hip_runtime.h>
#include <math.h>

#define NB 4
#define NN 4096
#define NS 32
#define NTOT (NB*NN*NS)   // 524288

__device__ __forceinline__ float lrelu(float x){ return x > 0.0f ? x : 0.2f*x; }

// ---------------- K1: ball query (first NS indices within radius, ascending) ----------------
__global__ __launch_bounds__(256) void k_ballquery(const float* __restrict__ pts, int* __restrict__ idx) {
  __shared__ float sx[NN], sy[NN], sz[NN], sq[NN];
  const int b = blockIdx.x >> 7;          // 128 tiles per batch
  const int tile = blockIdx.x & 127;      // 32 n per tile
  const float* p = pts + b*3*NN;
  for (int i = threadIdx.x; i < NN; i += 256) {
    float x = p[i], y = p[NN+i], z = p[2*NN+i];
    sx[i]=x; sy[i]=y; sz[i]=z;
    // match reference: sq = ((x*x + y*y) + z*z), no contraction
    sq[i] = __fadd_rn(__fadd_rn(__fmul_rn(x,x), __fmul_rn(y,y)), __fmul_rn(z,z));
  }
  __syncthreads();
  const int wave = threadIdx.x >> 6;
  const int lane = threadIdx.x & 63;
  for (int w = 0; w < 8; ++w) {
    const int n = tile*32 + wave*8 + w;
    const float cx = sx[n], cy = sy[n], cz = sz[n], cq = sq[n];
    int* row = idx + (((b << 12) + n) << 5);
    int count = 0;
    int first = 0;
    for (int jb = 0; jb < NN; jb += 64) {
      const int j = jb + lane;
      // dot via ascending FMA chain (Eigen sgemm K=3 order)
      float dot = fmaf(sz[j], cz, fmaf(sy[j], cy, __fmul_rn(sx[j], cx)));
      // 2*dot is exact (power-of-two), so single-rounded subtract either way
      float r = __fsub_rn(__fadd_rn(cq, sq[j]), __fmul_rn(2.0f, dot));
      bool valid = !(r > 0.04f);
      unsigned long long m = __ballot(valid);
      if (count == 0 && m != 0ull) first = jb + (int)__builtin_ctzll(m);
      int pos = count + (int)__popcll(m & ((1ull << lane) - 1ull));
      if (valid && pos < NS) row[pos] = j;
      count += (int)__popcll(m);
      if (count >= NS) break;   // count is wave-uniform
    }
    for (int pp = count + lane; pp < NS; pp += 64) row[pp] = first;
  }
}

// ---------------- K2: layer0 stats (no store) ----------------
__global__ __launch_bounds__(256) void k_stats0(const float* __restrict__ pts, const int* __restrict__ idx,
    const float* __restrict__ w0, const float* __restrict__ b0, float* __restrict__ part) {
  float ls[32], lq[32];
  #pragma unroll
  for (int c=0;c<32;c++){ ls[c]=0.f; lq[c]=0.f; }
  const int base = blockIdx.x * 2048;
  for (int k=0;k<8;k++){
    const int t = base + k*256 + (int)threadIdx.x;
    const int b = t >> 17;
    const int n = (t >> 5) & (NN-1);
    const int j = idx[t];
    const float* p = pts + b*3*NN;
    const float cx = p[n], cy = p[NN+n], cz = p[2*NN+n];
    const float e3 = p[j]-cx, e4 = p[NN+j]-cy, e5 = p[2*NN+j]-cz;
    #pragma unroll
    for (int c=0;c<32;c++){
      float v = b0[c];
      v = fmaf(cx, w0[c*6+0], v);
      v = fmaf(cy, w0[c*6+1], v);
      v = fmaf(cz, w0[c*6+2], v);
      v = fmaf(e3, w0[c*6+3], v);
      v = fmaf(e4, w0[c*6+4], v);
      v = fmaf(e5, w0[c*6+5], v);
      ls[c] += v; lq[c] = fmaf(v,v,lq[c]);
    }
  }
  #pragma unroll
  for (int off=32; off>=1; off>>=1){
    #pragma unroll
    for (int c=0;c<32;c++){ ls[c] += __shfl_xor(ls[c], off); lq[c] += __shfl_xor(lq[c], off); }
  }
  const int lane = threadIdx.x & 63;
  const int cl = lane & 31;
  float vs=0.f, vq=0.f;
  #pragma unroll
  for (int c=0;c<32;c++) if (cl==c){ vs=ls[c]; vq=lq[c]; }
  float* dst = part + (blockIdx.x*4 + (threadIdx.x>>6))*64;
  if (lane < 32) { dst[cl]=vs; dst[32+cl]=vq; }
}

// ---------------- finalize: partials -> scale/shift ----------------
__global__ __launch_bounds__(256) void k_fin(const float* __restrict__ part, int E, int C,
    const float* __restrict__ g, const float* __restrict__ beta, float* __restrict__ bn) {
  __shared__ float red[512];
  const int c = threadIdx.x & (C-1);
  const int sl = (int)threadIdx.x / C;
  const int nsl = 256 / C;
  float s=0.f, qq=0.f;
  for (int i=sl; i<E; i+=nsl){ s += part[i*2*C + c]; qq += part[i*2*C + C + c]; }
  red[threadIdx.x] = s; red[256 + threadIdx.x] = qq;
  __syncthreads();
  if ((int)threadIdx.x < C) {
    float ts=0.f, tq=0.f;
    for (int k2=0;k2<nsl;k2++){ ts += red[k2*C + c]; tq += red[256 + k2*C + c]; }
    const float inv = 1.0f / (float)NTOT;   // 2^-19, exact
    float m = ts * inv;
    float var = fmaxf(tq*inv - m*m, 0.0f);
    float sc = g[c] / sqrtf(var + 1e-5f);
    bn[c] = sc;
    bn[C+c] = beta[c] - m*sc;
  }
}

// ---------------- K3: layer0 (recompute) + bn0 + lrelu + layer1, store x1, stats1 ----------------
__global__ __launch_bounds__(256) void k_layer01(const float* __restrict__ pts, const int* __restrict__ idx,
    const float* __restrict__ w0, const float* __restrict__ b0, const float* __restrict__ bn0,
    const float* __restrict__ w1, const float* __restrict__ b1,
    float* __restrict__ x1, float* __restrict__ part) {
  float ls[32], lq[32];
  #pragma unroll
  for (int c=0;c<32;c++){ ls[c]=0.f; lq[c]=0.f; }
  const int base = blockIdx.x * 1024;
  for (int k=0;k<4;k++){
    const int t = base + k*256 + (int)threadIdx.x;
    const int b = t >> 17;
    const int n = (t >> 5) & (NN-1);
    const int j = idx[t];
    const float* p = pts + b*3*NN;
    const float cx = p[n], cy = p[NN+n], cz = p[2*NN+n];
    const float e3 = p[j]-cx, e4 = p[NN+j]-cy, e5 = p[2*NN+j]-cz;
    float h0[32];
    #pragma unroll
    for (int c=0;c<32;c++){
      float v = b0[c];
      v = fmaf(cx, w0[c*6+0], v);
      v = fmaf(cy, w0[c*6+1], v);
      v = fmaf(cz, w0[c*6+2], v);
      v = fmaf(e3, w0[c*6+3], v);
      v = fmaf(e4, w0[c*6+4], v);
      v = fmaf(e5, w0[c*6+5], v);
      h0[c] = lrelu(fmaf(v, bn0[c], bn0[32+c]));
    }
    float acc[32];
    #pragma unroll
    for (int o=0;o<32;o++){
      float a = b1[o];
      #pragma unroll
      for (int c=0;c<32;c++) a = fmaf(h0[c], w1[o*32+c], a);
      acc[o] = a;
      ls[o] += a; lq[o] = fmaf(a,a,lq[o]);
    }
    float4* dst4 = (float4*)(x1 + (size_t)t*32);
    #pragma unroll
    for (int u=0;u<8;u++) dst4[u] = make_float4(acc[4*u], acc[4*u+1], acc[4*u+2], acc[4*u+3]);
  }
  #pragma unroll
  for (int off=32; off>=1; off>>=1){
    #pragma unroll
    for (int c=0;c<32;c++){ ls[c] += __shfl_xor(ls[c], off); lq[c] += __shfl_xor(lq[c], off); }
  }
  const int lane = threadIdx.x & 63;
  const int cl = lane & 31;
  float vs=0.f, vq=0.f;
  #pragma unroll
  for (int c=0;c<32;c++) if (cl==c){ vs=ls[c]; vq=lq[c]; }
  float* dst = part + (blockIdx.x*4 + (threadIdx.x>>6))*64;
  if (lane < 32) { dst[cl]=vs; dst[32+cl]=vq; }
}

// ---------------- K4: bn1 + lrelu + layer2 stats (no store). wave owns a 16-channel quarter ----------------
__global__ __launch_bounds__(256) void k_stats2(const float* __restrict__ x1, const float* __restrict__ bn1,
    const float* __restrict__ w2, const float* __restrict__ b2, float* __restrict__ part) {
  const int wave = threadIdx.x >> 6;
  const int lane = threadIdx.x & 63;
  const int q16 = wave * 16;              // wave-uniform -> w2 reads stay scalar
  float ls[16], lq[16];
  #pragma unroll
  for (int i=0;i<16;i++){ ls[i]=0.f; lq[i]=0.f; }
  const int base = blockIdx.x * 1024;
  for (int k=0;k<16;k++){
    const int t = base + k*64 + lane;
    const float4* r4 = (const float4*)(x1 + (size_t)t*32);
    float hv[32];
    #pragma unroll
    for (int u=0;u<8;u++){
      float4 v4 = r4[u];
      hv[4*u+0] = lrelu(fmaf(v4.x, bn1[4*u+0], bn1[32+4*u+0]));
      hv[4*u+1] = lrelu(fmaf(v4.y, bn1[4*u+1], bn1[32+4*u+1]));
      hv[4*u+2] = lrelu(fmaf(v4.z, bn1[4*u+2], bn1[32+4*u+2]));
      hv[4*u+3] = lrelu(fmaf(v4.w, bn1[4*u+3], bn1[32+4*u+3]));
    }
    #pragma unroll
    for (int i=0;i<16;i++){
      float a = b2[q16+i];
      #pragma unroll
      for (int c=0;c<32;c++) a = fmaf(hv[c], w2[(q16+i)*32+c], a);
      ls[i] += a; lq[i] = fmaf(a,a,lq[i]);
    }
  }
  #pragma unroll
  for (int off=32; off>=1; off>>=1){
    #pragma unroll
    for (int i=0;i<16;i++){ ls[i] += __shfl_xor(ls[i], off); lq[i] += __shfl_xor(lq[i], off); }
  }
  const int cl = lane & 15;
  float vs=0.f, vq=0.f;
  #pragma unroll
  for (int i=0;i<16;i++) if (cl==i){ vs=ls[i]; vq=lq[i]; }
  float* dst = part + blockIdx.x*128;
  if (lane < 16){ dst[q16+cl] = vs; dst[64+q16+cl] = vq; }
}

// ---------------- K5: bn1+lrelu+layer2 (recompute)+bn2+lrelu, max over s, write (B,64,N) ----------------
__global__ __launch_bounds__(256) void k_final(const float* __restrict__ x1, const float* __restrict__ bn1,
    const float* __restrict__ w2, const float* __restrict__ b2, const float* __restrict__ bn2,
    float* __restrict__ out) {
  const int wave = threadIdx.x >> 6;
  const int lane = threadIdx.x & 63;
  const int q16 = wave * 16;              // wave-uniform channel quarter
  const int nl = lane & 31;
  const int sh = lane >> 5;
  const int b = blockIdx.x >> 7;
  const int n = ((blockIdx.x & 127) << 5) + nl;
  const int rowbase = (((b << 12) + n) << 5) + sh*16;
  float mx[16];
  #pragma unroll
  for (int i=0;i<16;i++) mx[i] = -3.0e38f;
  for (int s=0;s<16;s++){
    const float4* r4 = (const float4*)(x1 + (size_t)(rowbase + s)*32);
    float hv[32];
    #pragma unroll
    for (int u=0;u<8;u++){
      float4 v4 = r4[u];
      hv[4*u+0] = lrelu(fmaf(v4.x, bn1[4*u+0], bn1[32+4*u+0]));
      hv[4*u+1] = lrelu(fmaf(v4.y, bn1[4*u+1], bn1[32+4*u+1]));
      hv[4*u+2] = lrelu(fmaf(v4.z, bn1[4*u+2], bn1[32+4*u+2]));
      hv[4*u+3] = lrelu(fmaf(v4.w, bn1[4*u+3], bn1[32+4*u+3]));
    }
    #pragma unroll
    for (int i=0;i<16;i++){
      float a = b2[q16+i];
      #pragma unroll
      for (int c=0;c<32;c++) a = fmaf(hv[c], w2[(q16+i)*32+c], a);
      float v = lrelu(fmaf(a, bn2[q16+i], bn2[64+q16+i]));
      mx[i] = fmaxf(mx[i], v);
    }
  }
  #pragma unroll
  for (int i=0;i<16;i++) mx[i] = fmaxf(mx[i], __shfl_xor(mx[i], 32));
  if (sh == 0) {
    #pragma unroll
    for (int i=0;i<16;i++) out[(size_t)((b*64 + q16 + i) << 12) + n] = mx[i];
  }
}

extern "C" void kernel_launch(void* const* d_in, const int* in_sizes, int n_in,
                              void* d_out, int out_size, void* d_ws, size_t ws_size,
                              hipStream_t stream) {
  const float* pts = (const float*)d_in[0];
  const float* w0  = (const float*)d_in[1];
  const float* b0  = (const float*)d_in[2];
  const float* g0  = (const float*)d_in[3];
  const float* be0 = (const float*)d_in[4];
  const float* w1  = (const float*)d_in[5];
  const float* b1  = (const float*)d_in[6];
  const float* g1  = (const float*)d_in[7];
  const float* be1 = (const float*)d_in[8];
  const float* w2  = (const float*)d_in[9];
  const float* b2  = (const float*)d_in[10];
  const float* g2  = (const float*)d_in[11];
  const float* be2 = (const float*)d_in[12];
  float* out = (float*)d_out;

  char* ws = (char*)d_ws;
  int*   idx = (int*)  (ws + 0);           // 2 MB
  float* x1  = (float*)(ws + 2097152);     // 67.1 MB
  float* p0  = (float*)(ws + 69206016);    // 1024*64*4
  float* p1  = (float*)(ws + 69468160);    // 2048*64*4
  float* p2  = (float*)(ws + 69992448);    // 512*128*4
  float* bn0 = (float*)(ws + 70254592);
  float* bn1 = (float*)(ws + 70254848);
  float* bn2 = (float*)(ws + 70255104);

  k_ballquery<<<512, 256, 0, stream>>>(pts, idx);
  k_stats0  <<<256, 256, 0, stream>>>(pts, idx, w0, b0, p0);
  k_fin     <<<1,   256, 0, stream>>>(p0, 1024, 32, g0, be0, bn0);
  k_layer01 <<<512, 256, 0, stream>>>(pts, idx, w0, b0, bn0, w1, b1, x1, p1);
  k_fin     <<<1,   256, 0, stream>>>(p1, 2048, 32, g1, be1, bn1);
  k_stats2  <<<512, 256, 0, stream>>>(x1, bn1, w2, b2, p2);
  k_fin     <<<1,   256, 0, stream>>>(p2, 512, 64, g2, be2, bn2);
  k_final   <<<512, 256, 0, stream>>>(x1, bn1, w2, b2, bn2, out);
}